// Round 1
// baseline (925.534 us; speedup 1.0000x reference)
//
#include <hip/hip_runtime.h>
#include <math.h>

namespace {
constexpr int kB = 64;
constexpr int kH = 32;
constexpr int kHK = 8;
constexpr int kG = 4;        // GQA group size
constexpr int kD = 128;
constexpr int kBS = 16;      // page size
constexpr int kMaxCtx = 2048;
constexpr int kBPS = 128;    // blocks (pages) per sequence
constexpr float kScale = 0.08838834764831845f;
constexpr int kThreads = 512;
constexpr int kWaves = 8;
constexpr int kGroups = 32;  // 16-lane groups per block

__device__ __forceinline__ float dot8(const float4 a0, const float4 a1,
                                      const float4 b0, const float4 b1) {
    return a0.x * b0.x + a0.y * b0.y + a0.z * b0.z + a0.w * b0.w +
           a1.x * b1.x + a1.y * b1.y + a1.z * b1.z + a1.w * b1.w;
}

__device__ __forceinline__ void xred4(float4& v, int m) {
    v.x += __shfl_xor(v.x, m);
    v.y += __shfl_xor(v.y, m);
    v.z += __shfl_xor(v.z, m);
    v.w += __shfl_xor(v.w, m);
}
}  // namespace

extern "C" __global__ void __launch_bounds__(kThreads)
paged_attn_decode(const float* __restrict__ q,
                  const float* __restrict__ knew,
                  const float* __restrict__ vnew,
                  const float* __restrict__ kc,
                  const float* __restrict__ vc,
                  const int* __restrict__ btab,
                  const int* __restrict__ clen,
                  float* __restrict__ out) {
    __shared__ float s_sc[kG][kMaxCtx];   // 32 KB: scores, then p, then reused for partials
    __shared__ int s_bt[kBPS];
    __shared__ float s_wred[kWaves];
    __shared__ float s_inv[kG];

    const int bid = blockIdx.x;
    const int b = bid >> 3;
    const int kh = bid & 7;
    const int tid = threadIdx.x;
    const int lane = tid & 63;
    const int wave = tid >> 6;
    const int s = tid & 15;    // lane within 16-lane group
    const int grp = tid >> 4;  // global group id, 0..31

    const int ctx = clen[b];
    const int ctxm1 = ctx - 1;

    if (tid < kBPS) s_bt[tid] = btab[b * kBPS + tid];

    // q fragments: head h, dims [4s..4s+3] and [64+4s..64+4s+3]
    const float* qb = q + ((size_t)b * kH + (size_t)kh * kG) * kD;
    float4 q0[kG], q1[kG];
#pragma unroll
    for (int h = 0; h < kG; ++h) {
        q0[h] = *(const float4*)(qb + h * kD + 4 * s);
        q1[h] = *(const float4*)(qb + h * kD + 64 + 4 * s);
    }
    __syncthreads();

    // ---------------- Phase A: scores = q . K  (positions [0, ctx-1) from cache)
#pragma unroll 2
    for (int pos = grp; pos < ctxm1; pos += kGroups) {
        const int blk = s_bt[pos >> 4];
        const float* kr = kc + (((size_t)blk * kBS + (pos & 15)) * kHK + kh) * kD;
        const float4 ka = *(const float4*)(kr + 4 * s);
        const float4 kb2 = *(const float4*)(kr + 64 + 4 * s);
        float dh[kG];
#pragma unroll
        for (int h = 0; h < kG; ++h) dh[h] = dot8(ka, kb2, q0[h], q1[h]);
#pragma unroll
        for (int m = 1; m < 16; m <<= 1) {
#pragma unroll
            for (int h = 0; h < kG; ++h) dh[h] += __shfl_xor(dh[h], m);
        }
        if (s == 0) {
#pragma unroll
            for (int h = 0; h < kG; ++h) s_sc[h][pos] = dh[h] * kScale;
        }
    }
    // last position: fresh k input (reference scatters it into the cache first)
    if (grp == 0) {
        const float* kr = knew + ((size_t)b * kHK + kh) * kD;
        const float4 ka = *(const float4*)(kr + 4 * s);
        const float4 kb2 = *(const float4*)(kr + 64 + 4 * s);
        float dh[kG];
#pragma unroll
        for (int h = 0; h < kG; ++h) dh[h] = dot8(ka, kb2, q0[h], q1[h]);
#pragma unroll
        for (int m = 1; m < 16; m <<= 1) {
#pragma unroll
            for (int h = 0; h < kG; ++h) dh[h] += __shfl_xor(dh[h], m);
        }
        if (s == 0) {
#pragma unroll
            for (int h = 0; h < kG; ++h) s_sc[h][ctxm1] = dh[h] * kScale;
        }
    }
    __syncthreads();

    // ---------------- Phase B: softmax over [0, ctx) per head (2 waves per head)
    const int hof = tid >> 7;
    const int i0 = tid & 127;
    float mx = -INFINITY;
    for (int i = i0; i < ctx; i += 128) mx = fmaxf(mx, s_sc[hof][i]);
#pragma unroll
    for (int m = 1; m < 64; m <<= 1) mx = fmaxf(mx, __shfl_xor(mx, m));
    if (lane == 0) s_wred[wave] = mx;
    __syncthreads();
    const float hmax = fmaxf(s_wred[hof * 2], s_wred[hof * 2 + 1]);
    __syncthreads();  // all reads of s_wred done before reuse
    float sm = 0.f;
    for (int i = i0; i < ctx; i += 128) {
        const float e = __expf(s_sc[hof][i] - hmax);
        s_sc[hof][i] = e;
        sm += e;
    }
#pragma unroll
    for (int m = 1; m < 64; m <<= 1) sm += __shfl_xor(sm, m);
    if (lane == 0) s_wred[wave] = sm;
    __syncthreads();
    if (tid < kG) s_inv[tid] = 1.0f / (s_wred[tid * 2] + s_wred[tid * 2 + 1]);
    __syncthreads();

    // ---------------- Phase C: out = p . V
    float4 a0[kG], a1[kG];
#pragma unroll
    for (int h = 0; h < kG; ++h) {
        a0[h] = make_float4(0.f, 0.f, 0.f, 0.f);
        a1[h] = make_float4(0.f, 0.f, 0.f, 0.f);
    }
#pragma unroll 2
    for (int pos = grp; pos < ctxm1; pos += kGroups) {
        const int blk = s_bt[pos >> 4];
        const float* vr = vc + (((size_t)blk * kBS + (pos & 15)) * kHK + kh) * kD;
        const float4 va = *(const float4*)(vr + 4 * s);
        const float4 vb = *(const float4*)(vr + 64 + 4 * s);
#pragma unroll
        for (int h = 0; h < kG; ++h) {
            const float p = s_sc[h][pos];
            a0[h].x += p * va.x; a0[h].y += p * va.y; a0[h].z += p * va.z; a0[h].w += p * va.w;
            a1[h].x += p * vb.x; a1[h].y += p * vb.y; a1[h].z += p * vb.z; a1[h].w += p * vb.w;
        }
    }
    if (grp == 0) {
        const float* vr = vnew + ((size_t)b * kHK + kh) * kD;
        const float4 va = *(const float4*)(vr + 4 * s);
        const float4 vb = *(const float4*)(vr + 64 + 4 * s);
#pragma unroll
        for (int h = 0; h < kG; ++h) {
            const float p = s_sc[h][ctxm1];
            a0[h].x += p * va.x; a0[h].y += p * va.y; a0[h].z += p * va.z; a0[h].w += p * va.w;
            a1[h].x += p * vb.x; a1[h].y += p * vb.y; a1[h].z += p * vb.z; a1[h].w += p * vb.w;
        }
    }
    // reduce across the 4 groups of each wave (d-slices align across groups)
#pragma unroll
    for (int m = 16; m < 64; m <<= 1) {
#pragma unroll
        for (int h = 0; h < kG; ++h) {
            xred4(a0[h], m);
            xred4(a1[h], m);
        }
    }
    __syncthreads();  // everyone done reading p from s_sc; reuse as partial buffer
    float* s_part = &s_sc[0][0];  // [kWaves][512]
    if (lane < 16) {
#pragma unroll
        for (int h = 0; h < kG; ++h) {
            *(float4*)&s_part[wave * 512 + h * 128 + 4 * s] = a0[h];
            *(float4*)&s_part[wave * 512 + h * 128 + 64 + 4 * s] = a1[h];
        }
    }
    __syncthreads();
    float acc = 0.f;
#pragma unroll
    for (int w = 0; w < kWaves; ++w) acc += s_part[w * 512 + tid];
    out[(size_t)b * (kH * kD) + (size_t)kh * (kG * kD) + tid] = acc * s_inv[tid >> 7];
}

extern "C" void kernel_launch(void* const* d_in, const int* in_sizes, int n_in,
                              void* d_out, int out_size, void* d_ws, size_t ws_size,
                              hipStream_t stream) {
    const float* q = (const float*)d_in[0];
    const float* k = (const float*)d_in[1];
    const float* v = (const float*)d_in[2];
    const float* kc = (const float*)d_in[3];
    const float* vc = (const float*)d_in[4];
    // d_in[5] = slot_mapping: unused — the fresh k/v are read directly for pos ctx-1
    const int* bt = (const int*)d_in[6];
    const int* cl = (const int*)d_in[7];
    paged_attn_decode<<<dim3(kB * kHK), dim3(kThreads), 0, stream>>>(
        q, k, v, kc, vc, bt, cl, (float*)d_out);
}